// Round 2
// baseline (194.091 us; speedup 1.0000x reference)
//
#include <hip/hip_runtime.h>
#include <hip/hip_bf16.h>

// ---------------------------------------------------------------------------
// Hierarchical_CBlock: 15 pairwise GEMMs [16384x512]@[512x256] + bias + tanh
// + NAS mask, then final GEMM [16384x3840]@[3840x256] + bias.
// fp32 interfaces; bf16 internal MFMA (absmax 7.8e-3 vs 2.31e-2 threshold).
// Masked pairs skipped entirely. Structure: per-pair GEMM1(K=512)->tanh->LDS
// ->GEMM2(K=256), weight B-tiles staged via global_load_lds w=16
// (double-buffered), prefetch-chained across phases.
// R6: X-tile LDS dedup (bf16 staged once per block per kstep).
// R7: wave re-tile 16x128 -> 32x64 (6 b128 frag reads/wave/kstep, was 9).
//     Result: -1.8% => LDS-read port NOT critical path.
// R8: occupancy 1 -> 2 blocks/CU. Grid (256 token-blocks) x (2 pair-halves);
//     active pairs split by rank parity. Each block runs the identical inner
//     loop on its pair subset; GEMM2 partials combined via fp32 atomicAdd
//     into a zeroed output (b_final added by half 0). Two independent
//     barrier domains per CU hide the per-kstep __syncthreads vmcnt(0)
//     drain (1 block/CU had zero cross-block overlap). LDS 75KiB <= 80KiB,
//     launch_bounds(512,4) caps VGPR<=128 so both blocks co-reside.
// ---------------------------------------------------------------------------

typedef unsigned short u16;
typedef __bf16 bf16x8 __attribute__((ext_vector_type(8)));
typedef float f32x4 __attribute__((ext_vector_type(4)));

#define BS 16384      // B*S tokens
#define EMB 256
#define PAIRS 15
#define XRS 40        // ldsX row stride in bf16 (80B: 16B-aligned frags, balanced banks)

__constant__ int c_pi[PAIRS] = {0,0,0,0,0,1,1,1,1,2,2,2,3,3,4};
__constant__ int c_pj[PAIRS] = {1,2,3,4,5,2,3,4,5,3,4,5,4,5,5};

__device__ __forceinline__ u16 f2bf_u(float x) {
    __bf16 b = (__bf16)x;   // RTN
    return __builtin_bit_cast(u16, b);
}

// ============== merged transpose + fp32->bf16 convert ======================
// z < 15 : W_pair slab z  [512][256] -> [256][512]
// z == 15: W_final        [3840][256] -> [256][3840]
__global__ __launch_bounds__(256) void transpose_cvt2(
    const float* __restrict__ Wp, const float* __restrict__ Wf,
    u16* __restrict__ Wp_t, u16* __restrict__ Wf_t)
{
    __shared__ float t[32][33];
    const int z = blockIdx.z;
    const float* in;
    u16* out;
    int R;
    if (z < PAIRS) { R = 512;  in = Wp + (size_t)z * 512 * 256; out = Wp_t + (size_t)z * 256 * 512; }
    else           { R = 3840; in = Wf;                          out = Wf_t; }
    const int r0 = blockIdx.x * 32;
    if (r0 >= R) return;                    // block-uniform early exit
    const int c0 = blockIdx.y * 32;
    const int tr = threadIdx.x >> 5;
    const int tc = threadIdx.x & 31;
#pragma unroll
    for (int pass = 0; pass < 4; ++pass)
        t[pass * 8 + tr][tc] = in[(size_t)(r0 + pass * 8 + tr) * 256 + c0 + tc];
    __syncthreads();
#pragma unroll
    for (int pass = 0; pass < 4; ++pass)
        out[(size_t)(c0 + pass * 8 + tr) * R + r0 + tc] = f2bf_u(t[tc][pass * 8 + tr]);
}

// ============================ fused MFMA path ==============================

// Stage a 32k x 256n bf16 weight tile (16 KB) into LDS as 1024 16B chunks,
// chunk index = kb*256 + n. Source rows k-contiguous (transposed weights).
__device__ __forceinline__ void stage_tile(const u16* gsrc, int row_stride_us,
                                           int col_off_us, u16* lds_base, int tid) {
    int wave = tid >> 6;
#pragma unroll
    for (int r = 0; r < 2; ++r) {
        int c  = r * 512 + tid;
        int n  = c & 255;
        int kb = c >> 8;
        const u16* g = gsrc + (size_t)n * row_stride_us + col_off_us + kb * 8;
        u16* l = lds_base + (size_t)(r * 512 + wave * 64) * 8;  // wave-uniform
        __builtin_amdgcn_global_load_lds(
            (const __attribute__((address_space(1))) void*)g,
            (__attribute__((address_space(3))) void*)l,
            16, 0, 0);
    }
}

// Stage a 64-token x 32-k X-slice as bf16 into ldsX (4 KB, stride XRS).
// Thread t: row = t>>3, cols (t&7)*4 .. +3  (f32x4 load, 128B/8-thread rows).
__device__ __forceinline__ void stage_x(const float* fsrc, int t0, int col0,
                                        u16* ldsx, int tid) {
    const int row = tid >> 3;
    const int cg  = (tid & 7) * 4;
    f32x4 v = *(const f32x4*)(fsrc + (size_t)(t0 + row) * EMB + col0 + cg);
    ushort4 o;
    o.x = f2bf_u(v[0]); o.y = f2bf_u(v[1]); o.z = f2bf_u(v[2]); o.w = f2bf_u(v[3]);
    *(ushort4*)(ldsx + row * XRS + cg) = o;   // 8B store, 8B-aligned
}

__global__ __launch_bounds__(512, 4) void fused_cblock(
    const float* __restrict__ feats,   // [6][16384][256] fp32
    const u16* __restrict__ Wp_t,      // [15][256][512] bf16 (transposed)
    const float* __restrict__ b_pair,  // [15][256] fp32
    const u16* __restrict__ Wf_t,      // [256][3840] bf16 (transposed)
    const float* __restrict__ b_final, // [256] fp32
    const int* __restrict__ NAS,       // [6]
    float* __restrict__ out)           // [16384][256] fp32, pre-zeroed
{
    __shared__ u16 lds_b[2][8192];     // 2 x 16KB weight-tile double buffer
    __shared__ u16 lds_h[64 * 264];    // h tile bf16, stride 264 (16B-aligned)
    __shared__ u16 lds_x[2][64 * XRS]; // 2 x 5KB X-tile double buffer

    const int tid  = threadIdx.x;
    const int lane = tid & 63;
    const int wave = tid >> 6;
    const int wm   = wave & 1;         // 32-token slab
    const int wn   = wave >> 1;        // 64-col group (0..3)
    const int quad = lane >> 4;
    const int l16  = lane & 15;
    const int t0   = blockIdx.x * 64;
    const int half = blockIdx.y;       // pair-parity half (0 or 1)

    int nasv[6];
#pragma unroll
    for (int f = 0; f < 6; ++f) nasv[f] = (f < 2) ? 1 : (NAS[f] != 0 ? 1 : 0);
    // active pairs of THIS half: rank parity over the active-pair sequence
    int mymask = 0, rank = 0;
#pragma unroll
    for (int p = 0; p < PAIRS; ++p)
        if (nasv[c_pi[p]] & nasv[c_pj[p]]) {
            if ((rank & 1) == half) mymask |= (1 << p);
            ++rank;
        }
    if (mymask == 0) return;           // half 1 with <2 active pairs (uniform)

    // Entry prefetch: this half's first active pair.
    const int p0 = __builtin_ctz(mymask);
    stage_tile(Wp_t + (size_t)p0 * 256 * 512, 512, 0, lds_b[0], tid);
    stage_x(feats + (size_t)c_pi[p0] * BS * EMB, t0, 0, lds_x[0], tid);

    const f32x4 fzero = {0.f, 0.f, 0.f, 0.f};
    f32x4 acc2[8];                     // [mt*4+nt]: mt in {0,1}, nt in {0..3}
#pragma unroll
    for (int i = 0; i < 8; ++i) acc2[i] = fzero;

    __syncthreads();                    // drain entry prefetch (vm + lds)

    for (int p = 0; p < PAIRS; ++p) {
        if (!((mymask >> p) & 1)) continue;
        const int fi = c_pi[p], fj = c_pj[p];
        const u16* WpT = Wp_t + (size_t)p * 256 * 512;
        const int rest  = mymask >> (p + 1);
        const int pnext = rest ? (p + 1 + __builtin_ctz(rest)) : -1;

        // -------- GEMM1: h[64x256] = tanh(X[64x512] @ Wp + b) --------------
        // Precondition (prior barrier-drained): lds_b[0] = Wp_p k0,
        //                                       lds_x[0] = X(fi) k0.
        f32x4 acc1[8];
#pragma unroll
        for (int i = 0; i < 8; ++i) acc1[i] = fzero;

        for (int ks = 0; ks < 16; ++ks) {
            const int cur = ks & 1;
            if (ks < 15) {
                stage_tile(WpT, 512, (ks + 1) * 32, lds_b[1 - cur], tid);
                stage_x(feats + (size_t)((ks + 1 < 8) ? fi : fj) * BS * EMB,
                        t0, ((ks + 1) & 7) * 32, lds_x[1 - cur], tid);
            } else {
                stage_tile(Wf_t, 3840, p * 256, lds_b[1 - cur], tid); // GEMM2 k0
            }
            bf16x8 a0 = *(const bf16x8*)(&lds_x[cur][(wm * 32 + l16) * XRS + quad * 8]);
            bf16x8 a1 = *(const bf16x8*)(&lds_x[cur][(wm * 32 + 16 + l16) * XRS + quad * 8]);
#pragma unroll
            for (int nt = 0; nt < 4; ++nt) {
                const int n = wn * 64 + nt * 16 + l16;
                bf16x8 b = *(const bf16x8*)(&lds_b[cur][(quad * 256 + n) * 8]);
                acc1[nt]     = __builtin_amdgcn_mfma_f32_16x16x32_bf16(a0, b, acc1[nt],     0, 0, 0);
                acc1[4 + nt] = __builtin_amdgcn_mfma_f32_16x16x32_bf16(a1, b, acc1[4 + nt], 0, 0, 0);
            }
            __syncthreads();
        }

        // tanh + bias (fp32), h -> LDS bf16 (C-layout -> A-layout round trip)
#pragma unroll
        for (int mt = 0; mt < 2; ++mt)
#pragma unroll
        for (int nt = 0; nt < 4; ++nt) {
            const int n = wn * 64 + nt * 16 + l16;
            const float bias = b_pair[p * 256 + n];
#pragma unroll
            for (int r = 0; r < 4; ++r) {
                const int row = wm * 32 + mt * 16 + quad * 4 + r;  // C/D: row=quad*4+reg
                lds_h[row * 264 + n] = f2bf_u(tanhf(acc1[mt * 4 + nt][r] + bias));
            }
        }
        __syncthreads();   // publish lds_h (Wf k0 drained at ks=15 barrier)

        // -------- GEMM2: acc2 += h[64x256] @ Wf_p[256x256] ------------------
        for (int ks = 0; ks < 8; ++ks) {
            const int cur = ks & 1;
            if (ks < 7)
                stage_tile(Wf_t, 3840, p * 256 + (ks + 1) * 32, lds_b[1 - cur], tid);
            else if (pnext >= 0)   // prefetch next pair's Wp k0 -> buf0
                stage_tile(Wp_t + (size_t)pnext * 256 * 512, 512, 0, lds_b[1 - cur], tid);
            if (ks == 0 && pnext >= 0)  // prefetch next pair's X k0 -> xbuf0
                stage_x(feats + (size_t)c_pi[pnext] * BS * EMB, t0, 0, lds_x[0], tid);
            const int e0 = ks * 32 + quad * 8;
            bf16x8 a0 = *(const bf16x8*)(&lds_h[(wm * 32 + l16) * 264 + e0]);
            bf16x8 a1 = *(const bf16x8*)(&lds_h[(wm * 32 + 16 + l16) * 264 + e0]);
#pragma unroll
            for (int nt = 0; nt < 4; ++nt) {
                const int n = wn * 64 + nt * 16 + l16;
                bf16x8 b = *(const bf16x8*)(&lds_b[cur][(quad * 256 + n) * 8]);
                acc2[nt]     = __builtin_amdgcn_mfma_f32_16x16x32_bf16(a0, b, acc2[nt],     0, 0, 0);
                acc2[4 + nt] = __builtin_amdgcn_mfma_f32_16x16x32_bf16(a1, b, acc2[4 + nt], 0, 0, 0);
            }
            __syncthreads();
        }
    }

    // epilogue: atomic partial-sum into pre-zeroed out; half 0 carries b_final
#pragma unroll
    for (int mt = 0; mt < 2; ++mt)
#pragma unroll
    for (int nt = 0; nt < 4; ++nt) {
        const int n = wn * 64 + nt * 16 + l16;
        const float bf = (half == 0) ? b_final[n] : 0.f;
#pragma unroll
        for (int r = 0; r < 4; ++r) {
            const int t = t0 + wm * 32 + mt * 16 + quad * 4 + r;
            atomicAdd(&out[(size_t)t * EMB + n], acc2[mt * 4 + nt][r] + bf);
        }
    }
}

// ================== exact fp32 VALU fallback (ws-free) =====================

#define TOK 4

__global__ __launch_bounds__(256) void fallback_cblock(
    const float* __restrict__ feats, const float* __restrict__ W_pair,
    const float* __restrict__ b_pair, const float* __restrict__ W_final,
    const float* __restrict__ b_final, const int* __restrict__ NAS,
    float* __restrict__ out)
{
    __shared__ float xs[TOK][6 * 256];
    __shared__ float hf[TOK][PAIRS * 256];

    const int n  = threadIdx.x;
    const int t0 = blockIdx.x * TOK;

#pragma unroll
    for (int tk = 0; tk < TOK; ++tk)
#pragma unroll
        for (int f = 0; f < 6; ++f)
            xs[tk][f * 256 + n] = feats[((size_t)f * BS + t0 + tk) * EMB + n];
    __syncthreads();

    int nasv[6];
#pragma unroll
    for (int f = 0; f < 6; ++f) nasv[f] = (f < 2) ? 1 : (NAS[f] != 0 ? 1 : 0);

    for (int p = 0; p < PAIRS; ++p) {
        const int fi = c_pi[p], fj = c_pj[p];
        if (!(nasv[fi] & nasv[fj])) {
#pragma unroll
            for (int tk = 0; tk < TOK; ++tk) hf[tk][p * 256 + n] = 0.f;
            continue;
        }
        float acc[TOK];
        const float bias = b_pair[p * 256 + n];
#pragma unroll
        for (int tk = 0; tk < TOK; ++tk) acc[tk] = bias;
        const float* Wp = W_pair + (size_t)p * 512 * 256;
#pragma unroll 4
        for (int k = 0; k < 512; ++k) {
            const float w = Wp[(size_t)k * 256 + n];
            const int xoff = ((k < 256) ? fi : fj) * 256 + (k & 255);
#pragma unroll
            for (int tk = 0; tk < TOK; ++tk) acc[tk] += xs[tk][xoff] * w;
        }
#pragma unroll
        for (int tk = 0; tk < TOK; ++tk)
            hf[tk][p * 256 + n] = tanhf(acc[tk]);
    }
    __syncthreads();

    float acc[TOK];
    const float bf = b_final[n];
#pragma unroll
    for (int tk = 0; tk < TOK; ++tk) acc[tk] = bf;
#pragma unroll 4
    for (int k = 0; k < PAIRS * 256; ++k) {
        const float w = W_final[(size_t)k * 256 + n];
#pragma unroll
        for (int tk = 0; tk < TOK; ++tk) acc[tk] += hf[tk][k] * w;
    }
#pragma unroll
    for (int tk = 0; tk < TOK; ++tk)
        out[(size_t)(t0 + tk) * EMB + n] = acc[tk];
}

// ===========================================================================

extern "C" void kernel_launch(void* const* d_in, const int* in_sizes, int n_in,
                              void* d_out, int out_size, void* d_ws, size_t ws_size,
                              hipStream_t stream) {
    const float* feats   = (const float*)d_in[0];
    const float* W_pair  = (const float*)d_in[1];
    const float* b_pair  = (const float*)d_in[2];
    const float* W_final = (const float*)d_in[3];
    const float* b_final = (const float*)d_in[4];
    const int*   NAS     = (const int*)d_in[5];

    const size_t needed = ((size_t)PAIRS * 256 * 512 + (size_t)256 * 3840) * 2;

    if (ws_size >= needed) {
        u16* Wp_t = (u16*)d_ws;                         // 15*256*512 bf16
        u16* Wf_t = Wp_t + (size_t)PAIRS * 256 * 512;   // 256*3840 bf16
        hipMemsetAsync(d_out, 0, out_size, stream);     // atomic partial-sum target
        transpose_cvt2<<<dim3(3840 / 32, 256 / 32, PAIRS + 1), 256, 0, stream>>>(
            W_pair, W_final, Wp_t, Wf_t);
        fused_cblock<<<dim3(BS / 64, 2), 512, 0, stream>>>(feats, Wp_t, b_pair,
                                                           Wf_t, b_final, NAS,
                                                           (float*)d_out);
    } else {
        fallback_cblock<<<BS / TOK, 256, 0, stream>>>(feats, W_pair, b_pair,
                                                      W_final, b_final, NAS,
                                                      (float*)d_out);
    }
}

// Round 3
// 178.878 us; speedup vs baseline: 1.0850x; 1.0850x over previous
//
#include <hip/hip_runtime.h>
#include <hip/hip_bf16.h>

// ---------------------------------------------------------------------------
// Hierarchical_CBlock: 15 pairwise GEMMs [16384x512]@[512x256] + bias + tanh
// + NAS mask, then final GEMM [16384x3840]@[3840x256] + bias.
// fp32 interfaces; bf16 internal MFMA (absmax 7.8e-3 vs 2.31e-2 threshold).
// R7: wave tile 32x64 (6 b128 frag reads/wave/kstep). -1.8% => not LDS-bound.
// R8: 2 blocks/CU attempt: occupancy did NOT double (LDS), atomics cost +14us.
//     REVERTED. Counters: fused = ~59us, MfmaUtil 3.9%, VALU 10%, HBM 7%
//     => pure latency/stall-bound on the per-kstep barrier drain.
// R9: counted-vmcnt pipeline (T3/T4-lite):
//     - lds_b triple buffer; per step issue tile(g+2); raw s_barrier with
//       manual "s_waitcnt vmcnt(2) lgkmcnt(0)" (never vmcnt(0) in loop).
//       In-order vmcnt => tile(g) provably complete, tile(g+1..2) in flight.
//     - X staging split load-early/write-late (T14): f32x4 load issued at
//       step start (before tiles, so the auto-wait at the write retires x
//       but keeps the newest tile flying), cvt+ds_write after MFMA phase.
//     - sched_barrier(0) pins phase order vs compiler reordering.
//     - b_pair biases preloaded to LDS (no stray VMEM in steady state).
//     - uniform dummy issues at the tail + final vmcnt(0) drain.
// ---------------------------------------------------------------------------

typedef unsigned short u16;
typedef __bf16 bf16x8 __attribute__((ext_vector_type(8)));
typedef float f32x4 __attribute__((ext_vector_type(4)));

#define BS 16384      // B*S tokens
#define EMB 256
#define PAIRS 15
#define XRS 40        // ldsX row stride in bf16 (80B: 16B-aligned frags)

__constant__ int c_pi[PAIRS] = {0,0,0,0,0,1,1,1,1,2,2,2,3,3,4};
__constant__ int c_pj[PAIRS] = {1,2,3,4,5,2,3,4,5,3,4,5,4,5,5};

__device__ __forceinline__ u16 f2bf_u(float x) {
    __bf16 b = (__bf16)x;   // RTN
    return __builtin_bit_cast(u16, b);
}

// ============== merged transpose + fp32->bf16 convert ======================
__global__ __launch_bounds__(256) void transpose_cvt2(
    const float* __restrict__ Wp, const float* __restrict__ Wf,
    u16* __restrict__ Wp_t, u16* __restrict__ Wf_t)
{
    __shared__ float t[32][33];
    const int z = blockIdx.z;
    const float* in;
    u16* out;
    int R;
    if (z < PAIRS) { R = 512;  in = Wp + (size_t)z * 512 * 256; out = Wp_t + (size_t)z * 256 * 512; }
    else           { R = 3840; in = Wf;                          out = Wf_t; }
    const int r0 = blockIdx.x * 32;
    if (r0 >= R) return;                    // block-uniform early exit
    const int c0 = blockIdx.y * 32;
    const int tr = threadIdx.x >> 5;
    const int tc = threadIdx.x & 31;
#pragma unroll
    for (int pass = 0; pass < 4; ++pass)
        t[pass * 8 + tr][tc] = in[(size_t)(r0 + pass * 8 + tr) * 256 + c0 + tc];
    __syncthreads();
#pragma unroll
    for (int pass = 0; pass < 4; ++pass)
        out[(size_t)(c0 + pass * 8 + tr) * R + r0 + tc] = f2bf_u(t[tc][pass * 8 + tr]);
}

// ============================ fused MFMA path ==============================

// Stage a 32k x 256n bf16 weight tile (16 KB) into LDS as 1024 16B chunks.
__device__ __forceinline__ void stage_tile(const u16* gsrc, int row_stride_us,
                                           int col_off_us, u16* lds_base, int tid) {
    int wave = tid >> 6;
#pragma unroll
    for (int r = 0; r < 2; ++r) {
        int c  = r * 512 + tid;
        int n  = c & 255;
        int kb = c >> 8;
        const u16* g = gsrc + (size_t)n * row_stride_us + col_off_us + kb * 8;
        u16* l = lds_base + (size_t)(r * 512 + wave * 64) * 8;  // wave-uniform
        __builtin_amdgcn_global_load_lds(
            (const __attribute__((address_space(1))) void*)g,
            (__attribute__((address_space(3))) void*)l,
            16, 0, 0);
    }
}

// Uniform per-step sync: prev tile (g) complete, newest tile (g+1/g+2) and
// x-load stay in flight. NEVER vmcnt(0) in the main loop.
__device__ __forceinline__ void phase_barrier() {
    asm volatile("s_waitcnt vmcnt(2) lgkmcnt(0)" ::: "memory");
    __builtin_amdgcn_sched_barrier(0);
    __builtin_amdgcn_s_barrier();
    __builtin_amdgcn_sched_barrier(0);
}

__global__ __launch_bounds__(512, 2) void fused_cblock(
    const float* __restrict__ feats,   // [6][16384][256] fp32
    const u16* __restrict__ Wp_t,      // [15][256][512] bf16 (transposed)
    const float* __restrict__ b_pair,  // [15][256] fp32
    const u16* __restrict__ Wf_t,      // [256][3840] bf16 (transposed)
    const float* __restrict__ b_final, // [256] fp32
    const int* __restrict__ NAS,       // [6]
    float* __restrict__ out)           // [16384][256] fp32
{
    __shared__ u16   lds_b[3][8192];       // 3 x 16KB weight-tile rotation
    __shared__ u16   lds_h[64 * 264];      // h tile bf16, stride 264
    __shared__ u16   lds_x[2][64 * XRS];   // 2 x 5KB X-tile double buffer
    __shared__ float lds_bias[PAIRS * 256];// 15KB b_pair preload

    const int tid  = threadIdx.x;
    const int lane = tid & 63;
    const int wave = tid >> 6;
    const int wm   = wave & 1;         // 32-token slab
    const int wn   = wave >> 1;        // 64-col group (0..3)
    const int quad = lane >> 4;
    const int l16  = lane & 15;
    const int t0   = blockIdx.x * 64;
    const int xrow = tid >> 3;         // x-staging row (0..63)
    const int xcg  = (tid & 7) * 4;    // x-staging col group

    int nasv[6];
#pragma unroll
    for (int f = 0; f < 6; ++f) nasv[f] = (f < 2) ? 1 : (NAS[f] != 0 ? 1 : 0);
    int pmask = 0;
#pragma unroll
    for (int p = 0; p < PAIRS; ++p)
        if (nasv[c_pi[p]] & nasv[c_pj[p]]) pmask |= (1 << p);
    // pair 0 always active (features 0,1 forced on) => pmask bit0 == 1.

    // ---- prologue: bias preload, x slice0, weight tiles k0/k1 -------------
    float btmp[8];
#pragma unroll
    for (int i = 0; i < 8; ++i) {
        const int idx = tid + i * 512;
        btmp[i] = (idx < PAIRS * 256) ? b_pair[idx] : 0.f;
    }
#pragma unroll
    for (int i = 0; i < 8; ++i) {
        const int idx = tid + i * 512;
        if (idx < PAIRS * 256) lds_bias[idx] = btmp[i];
    }
    // x slice0 of pair0 (feature 0), then the two weight tiles
    f32x4 xv = *(const f32x4*)(feats + (size_t)(t0 + xrow) * EMB + xcg);
    stage_tile(Wp_t, 512, 0,  lds_b[0], tid);
    stage_tile(Wp_t, 512, 32, lds_b[1], tid);
    {   // finish x staging (auto-wait keeps the 4 tile ops in flight)
        ushort4 o;
        o.x = f2bf_u(xv[0]); o.y = f2bf_u(xv[1]);
        o.z = f2bf_u(xv[2]); o.w = f2bf_u(xv[3]);
        *(ushort4*)(&lds_x[0][xrow * XRS + xcg]) = o;
    }

    const f32x4 fzero = {0.f, 0.f, 0.f, 0.f};
    f32x4 acc2[8];
#pragma unroll
    for (int i = 0; i < 8; ++i) acc2[i] = fzero;

    int bcur = 0, bw = 2;              // lds_b read / write rotation (mod 3)

    for (int p = 0; p < PAIRS; ++p) {
        if (!((pmask >> p) & 1)) continue;          // block-uniform
        const int fi = c_pi[p], fj = c_pj[p];
        const u16* WpT = Wp_t + (size_t)p * 256 * 512;
        const int rest  = pmask >> (p + 1);
        const int pnext = rest ? (p + 1 + __builtin_ctz(rest)) : -1;

        // -------- GEMM1: h[64x256] = tanh(X[64x512] @ Wp + b) --------------
        f32x4 acc1[8];
#pragma unroll
        for (int i = 0; i < 8; ++i) acc1[i] = fzero;

        for (int ks = 0; ks < 16; ++ks) {
            phase_barrier();           // tile(g) ready for ALL waves
            // ---- A1: x-load for slice ks+1 (slice16 = next pair slice0) --
            const int sl = ks + 1;
            const float* xsrc;
            int xcol;
            if (sl < 16) {
                xsrc = feats + (size_t)((sl < 8) ? fi : fj) * BS * EMB;
                xcol = (sl & 7) * 32;
            } else {
                const int nf = (pnext >= 0) ? c_pi[pnext] : fi;  // dummy if last
                xsrc = feats + (size_t)nf * BS * EMB;
                xcol = 0;
            }
            f32x4 v = *(const f32x4*)(xsrc + (size_t)(t0 + xrow) * EMB + xcol + xcg);
            __builtin_amdgcn_sched_barrier(0);     // x-load issued BEFORE tiles
            // ---- A2: weight tile for step g+2 ----------------------------
            {
                const u16* gp; int rs, co;
                const int idx = ks + 2;
                if (idx <= 15)      { gp = WpT;  rs = 512;  co = idx * 32; }
                else if (idx == 16) { gp = Wf_t; rs = 3840; co = p * 256; }
                else                { gp = Wf_t; rs = 3840; co = p * 256 + 32; }
                stage_tile(gp, rs, co, lds_b[bw], tid);
            }
            __builtin_amdgcn_sched_barrier(0);     // tiles issued BEFORE compute
            // ---- C: MFMA from lds_b[bcur], lds_x[ks&1] -------------------
            bf16x8 a0 = *(const bf16x8*)(&lds_x[ks & 1][(wm * 32 + l16) * XRS + quad * 8]);
            bf16x8 a1 = *(const bf16x8*)(&lds_x[ks & 1][(wm * 32 + 16 + l16) * XRS + quad * 8]);
#pragma unroll
            for (int nt = 0; nt < 4; ++nt) {
                const int n = wn * 64 + nt * 16 + l16;
                bf16x8 b = *(const bf16x8*)(&lds_b[bcur][(quad * 256 + n) * 8]);
                acc1[nt]     = __builtin_amdgcn_mfma_f32_16x16x32_bf16(a0, b, acc1[nt],     0, 0, 0);
                acc1[4 + nt] = __builtin_amdgcn_mfma_f32_16x16x32_bf16(a1, b, acc1[4 + nt], 0, 0, 0);
            }
            __builtin_amdgcn_sched_barrier(0);     // keep D after C
            // ---- D: finish x staging into lds_x[(ks+1)&1] ----------------
            {   // auto vmcnt wait here retires v (+older tile), newest flies
                ushort4 o;
                o.x = f2bf_u(v[0]); o.y = f2bf_u(v[1]);
                o.z = f2bf_u(v[2]); o.w = f2bf_u(v[3]);
                *(ushort4*)(&lds_x[sl & 1][xrow * XRS + xcg]) = o;
            }
            bcur = (bcur == 2) ? 0 : bcur + 1;
            bw   = (bw   == 2) ? 0 : bw   + 1;
        }

        // tanh + bias (bias from LDS: no VMEM in steady state)
#pragma unroll
        for (int nt = 0; nt < 4; ++nt) {
            const int n = wn * 64 + nt * 16 + l16;
            const float bias = lds_bias[p * 256 + n];
#pragma unroll
            for (int mt = 0; mt < 2; ++mt)
#pragma unroll
            for (int r = 0; r < 4; ++r) {
                const int row = wm * 32 + mt * 16 + quad * 4 + r;
                lds_h[row * 264 + n] = f2bf_u(tanhf(acc1[mt * 4 + nt][r] + bias));
            }
        }
        // lds_h publish is covered by the next phase_barrier (lgkmcnt(0)+bar)

        // -------- GEMM2: acc2 += h[64x256] @ Wf_p[256x256] ------------------
        for (int ks = 0; ks < 8; ++ks) {
            phase_barrier();           // tile(g) ready + lds_h published
            // ---- A: weight tile for step g+2 (tail: next pair Wp / dummy) -
            {
                const u16* gp; int rs, co;
                const int idx = ks + 2;
                if (idx <= 7) { gp = Wf_t; rs = 3840; co = p * 256 + idx * 32; }
                else {
                    const int np = (pnext >= 0) ? pnext : p;   // dummy reload
                    gp = Wp_t + (size_t)np * 256 * 512; rs = 512; co = (idx - 8) * 32;
                }
                stage_tile(gp, rs, co, lds_b[bw], tid);
            }
            __builtin_amdgcn_sched_barrier(0);
            // ---- C: MFMA from lds_h / lds_b[bcur] ------------------------
            const int e0 = ks * 32 + quad * 8;
            bf16x8 a0 = *(const bf16x8*)(&lds_h[(wm * 32 + l16) * 264 + e0]);
            bf16x8 a1 = *(const bf16x8*)(&lds_h[(wm * 32 + 16 + l16) * 264 + e0]);
#pragma unroll
            for (int nt = 0; nt < 4; ++nt) {
                const int n = wn * 64 + nt * 16 + l16;
                bf16x8 b = *(const bf16x8*)(&lds_b[bcur][(quad * 256 + n) * 8]);
                acc2[nt]     = __builtin_amdgcn_mfma_f32_16x16x32_bf16(a0, b, acc2[nt],     0, 0, 0);
                acc2[4 + nt] = __builtin_amdgcn_mfma_f32_16x16x32_bf16(a1, b, acc2[4 + nt], 0, 0, 0);
            }
            __builtin_amdgcn_sched_barrier(0);
            bcur = (bcur == 2) ? 0 : bcur + 1;
            bw   = (bw   == 2) ? 0 : bw   + 1;
        }
    }

    // drain dummy/tail loads before LDS goes out of scope & epilogue
    asm volatile("s_waitcnt vmcnt(0)" ::: "memory");

    // epilogue: + b_final, fp32 store
#pragma unroll
    for (int mt = 0; mt < 2; ++mt)
#pragma unroll
    for (int nt = 0; nt < 4; ++nt) {
        const int n = wn * 64 + nt * 16 + l16;
        const float bf = b_final[n];
#pragma unroll
        for (int r = 0; r < 4; ++r) {
            const int t = t0 + wm * 32 + mt * 16 + quad * 4 + r;
            out[(size_t)t * EMB + n] = acc2[mt * 4 + nt][r] + bf;
        }
    }
}

// ================== exact fp32 VALU fallback (ws-free) =====================

#define TOK 4

__global__ __launch_bounds__(256) void fallback_cblock(
    const float* __restrict__ feats, const float* __restrict__ W_pair,
    const float* __restrict__ b_pair, const float* __restrict__ W_final,
    const float* __restrict__ b_final, const int* __restrict__ NAS,
    float* __restrict__ out)
{
    __shared__ float xs[TOK][6 * 256];
    __shared__ float hf[TOK][PAIRS * 256];

    const int n  = threadIdx.x;
    const int t0 = blockIdx.x * TOK;

#pragma unroll
    for (int tk = 0; tk < TOK; ++tk)
#pragma unroll
        for (int f = 0; f < 6; ++f)
            xs[tk][f * 256 + n] = feats[((size_t)f * BS + t0 + tk) * EMB + n];
    __syncthreads();

    int nasv[6];
#pragma unroll
    for (int f = 0; f < 6; ++f) nasv[f] = (f < 2) ? 1 : (NAS[f] != 0 ? 1 : 0);

    for (int p = 0; p < PAIRS; ++p) {
        const int fi = c_pi[p], fj = c_pj[p];
        if (!(nasv[fi] & nasv[fj])) {
#pragma unroll
            for (int tk = 0; tk < TOK; ++tk) hf[tk][p * 256 + n] = 0.f;
            continue;
        }
        float acc[TOK];
        const float bias = b_pair[p * 256 + n];
#pragma unroll
        for (int tk = 0; tk < TOK; ++tk) acc[tk] = bias;
        const float* Wp = W_pair + (size_t)p * 512 * 256;
#pragma unroll 4
        for (int k = 0; k < 512; ++k) {
            const float w = Wp[(size_t)k * 256 + n];
            const int xoff = ((k < 256) ? fi : fj) * 256 + (k & 255);
#pragma unroll
            for (int tk = 0; tk < TOK; ++tk) acc[tk] += xs[tk][xoff] * w;
        }
#pragma unroll
        for (int tk = 0; tk < TOK; ++tk)
            hf[tk][p * 256 + n] = tanhf(acc[tk]);
    }
    __syncthreads();

    float acc[TOK];
    const float bf = b_final[n];
#pragma unroll
    for (int tk = 0; tk < TOK; ++tk) acc[tk] = bf;
#pragma unroll 4
    for (int k = 0; k < PAIRS * 256; ++k) {
        const float w = W_final[(size_t)k * 256 + n];
#pragma unroll
        for (int tk = 0; tk < TOK; ++tk) acc[tk] += hf[tk][k] * w;
    }
#pragma unroll
    for (int tk = 0; tk < TOK; ++tk)
        out[(size_t)(t0 + tk) * EMB + n] = acc[tk];
}

// ===========================================================================

extern "C" void kernel_launch(void* const* d_in, const int* in_sizes, int n_in,
                              void* d_out, int out_size, void* d_ws, size_t ws_size,
                              hipStream_t stream) {
    const float* feats   = (const float*)d_in[0];
    const float* W_pair  = (const float*)d_in[1];
    const float* b_pair  = (const float*)d_in[2];
    const float* W_final = (const float*)d_in[3];
    const float* b_final = (const float*)d_in[4];
    const int*   NAS     = (const int*)d_in[5];

    const size_t needed = ((size_t)PAIRS * 256 * 512 + (size_t)256 * 3840) * 2;

    if (ws_size >= needed) {
        u16* Wp_t = (u16*)d_ws;                         // 15*256*512 bf16
        u16* Wf_t = Wp_t + (size_t)PAIRS * 256 * 512;   // 256*3840 bf16
        transpose_cvt2<<<dim3(3840 / 32, 256 / 32, PAIRS + 1), 256, 0, stream>>>(
            W_pair, W_final, Wp_t, Wf_t);
        fused_cblock<<<BS / 64, 512, 0, stream>>>(feats, Wp_t, b_pair, Wf_t,
                                                  b_final, NAS, (float*)d_out);
    } else {
        fallback_cblock<<<BS / TOK, 256, 0, stream>>>(feats, W_pair, b_pair,
                                                      W_final, b_final, NAS,
                                                      (float*)d_out);
    }
}